// Round 1
// baseline (81.190 us; speedup 1.0000x reference)
//
#include <hip/hip_runtime.h>

#define NG  512
#define WIN 64
#define NH1 128
#define NH2 128
#define NH3 64
#define NBB 1024
#define GW  (NG*WIN)    // 32768
#define GH3 (NG*NH3)    // 32768

typedef __attribute__((ext_vector_type(8))) short bf16x8;
typedef __attribute__((ext_vector_type(4))) float f32x4;
typedef __attribute__((ext_vector_type(4))) unsigned int u32x4;

union frag_u { u32x4 u; bf16x8 h; };

// pack two floats -> two bf16 (RNE), low half = a
__device__ __forceinline__ unsigned pk2bf(float a, float b) {
  unsigned ua = __builtin_bit_cast(unsigned, a);
  unsigned ub = __builtin_bit_cast(unsigned, b);
  ua += 0x7fffu + ((ua >> 16) & 1u);
  ub += 0x7fffu + ((ub >> 16) & 1u);
  return (ua >> 16) | (ub & 0xffff0000u);
}

// (E,O) packed D-words -> (w_p, w_{p+2}) B-operand words via half/row swaps.
// s_nop padding: compiler can't see hazards inside asm.
__device__ __forceinline__ void permswap(unsigned &e, unsigned &o) {
  asm volatile("s_nop 1\n\t"
               "v_permlane32_swap_b32 %0, %1\n\t"
               "s_nop 1\n\t"
               "v_permlane16_swap_b32 %0, %1\n\t"
               "s_nop 1"
               : "+v"(e), "+v"(o));
}

// Stage W[g] ([K][H] fp32, row-major) into LDS as Wt[h][k] bf16,
// 16B slots XOR-swizzled: slot' = kb ^ (h&7). Coalesced global reads.
template<int K, int H>
__device__ __forceinline__ void stage(const float* __restrict__ gsrc,
                                      unsigned short* ldsBase, int tid) {
  constexpr int NELEM = (K / 8) * H;   // one b128 store per element
  #pragma unroll
  for (int lin = tid; lin < NELEM; lin += 512) {
    const int h  = lin & (H - 1);
    const int kb = lin / H;            // k-octet index
    const float* p = gsrc + h + (size_t)(8 * kb) * H;
    unsigned w0 = pk2bf(p[0 * H], p[1 * H]);
    unsigned w1 = pk2bf(p[2 * H], p[3 * H]);
    unsigned w2 = pk2bf(p[4 * H], p[5 * H]);
    unsigned w3 = pk2bf(p[6 * H], p[7 * H]);
    const int byteoff = h * (2 * K) + 16 * (kb ^ (h & 7));
    *(u32x4*)((char*)ldsBase + byteoff) = (u32x4){w0, w1, w2, w3};
  }
}

// Build 4 B-fragments (K=128) for the next layer from 8 D-tiles (h tiles).
__device__ __forceinline__ void mk_bfrag(const f32x4* acc, frag_u* bf) {
  #pragma unroll
  for (int kc = 0; kc < 4; ++kc) {
    f32x4 e = acc[2 * kc], o = acc[2 * kc + 1];
    unsigned E0 = pk2bf(fmaxf(e[0], 0.f), fmaxf(e[1], 0.f));
    unsigned E1 = pk2bf(fmaxf(e[2], 0.f), fmaxf(e[3], 0.f));
    unsigned O0 = pk2bf(fmaxf(o[0], 0.f), fmaxf(o[1], 0.f));
    unsigned O1 = pk2bf(fmaxf(o[2], 0.f), fmaxf(o[3], 0.f));
    permswap(E0, O0);   // -> w0, w2
    permswap(E1, O1);   // -> w1, w3
    bf[kc].u = (u32x4){E0, E1, O0, O1};
  }
}

__global__ __launch_bounds__(512, 4)
void DeepBlockDense_kernel(const float* __restrict__ x,
                           const float* __restrict__ w1,
                           const float* __restrict__ w2,
                           const float* __restrict__ w3,
                           float* __restrict__ out) {
  __shared__ __align__(16) unsigned short smem[32768];  // 64 KB bf16 weights
  const int g    = blockIdx.x;
  const int tid  = threadIdx.x;
  const int lane = tid & 63;
  const int wid  = tid >> 6;     // 0..7
  const int bq   = lane >> 4;    // k-octet / D-row-quad
  const int bl   = lane & 15;    // batch col (B-op) / h row (A-op)

  // ---- stage weights transposed into LDS
  stage<64 , 128>(w1 + (size_t)g * (64 * 128) , smem        , tid); // Wt1 [128][64]
  stage<128, 128>(w2 + (size_t)g * (128 * 128), smem + 8192 , tid); // Wt2 [128][128]
  stage<128, 64 >(w3 + (size_t)g * (128 * 64) , smem + 24576, tid); // Wt3 [64][128]
  __syncthreads();

  const char* wt1 = (const char*)smem;
  const char* wt2 = (const char*)(smem + 8192);
  const char* wt3 = (const char*)(smem + 24576);

  #pragma unroll 1
  for (int t = 0; t < 8; ++t) {
    const size_t brow = (size_t)(t * 128 + wid * 16 + bl);

    // ---- layer-1 B fragments straight from global (x^T layout is free)
    frag_u b1[2];
    {
      const float* px = x + brow * GW + g * 64 + 8 * bq;
      #pragma unroll
      for (int kc = 0; kc < 2; ++kc) {
        f32x4 lo = *(const f32x4*)(px + 32 * kc);
        f32x4 hi = *(const f32x4*)(px + 32 * kc + 4);
        b1[kc].u = (u32x4){pk2bf(lo[0], lo[1]), pk2bf(lo[2], lo[3]),
                           pk2bf(hi[0], hi[1]), pk2bf(hi[2], hi[3])};
      }
    }

    // ---- layer 1: D1[h][b], M=128 K=64
    f32x4 acc1[8] = {};
    #pragma unroll
    for (int mt = 0; mt < 8; ++mt) {
      const int h = 16 * mt + bl;
      #pragma unroll
      for (int kc = 0; kc < 2; ++kc) {
        frag_u a;
        a.u = *(const u32x4*)(wt1 + h * 128 + 16 * ((4 * kc + bq) ^ (h & 7)));
        acc1[mt] = __builtin_amdgcn_mfma_f32_16x16x32_bf16(a.h, b1[kc].h, acc1[mt], 0, 0, 0);
      }
    }

    frag_u b2[4];
    mk_bfrag(acc1, b2);

    // ---- layer 2: M=128 K=128
    f32x4 acc2[8] = {};
    #pragma unroll
    for (int mt = 0; mt < 8; ++mt) {
      const int h = 16 * mt + bl;
      #pragma unroll
      for (int kc = 0; kc < 4; ++kc) {
        frag_u a;
        a.u = *(const u32x4*)(wt2 + h * 256 + 16 * ((4 * kc + bq) ^ (h & 7)));
        acc2[mt] = __builtin_amdgcn_mfma_f32_16x16x32_bf16(a.h, b2[kc].h, acc2[mt], 0, 0, 0);
      }
    }

    frag_u b3[4];
    mk_bfrag(acc2, b3);

    // ---- layer 3: M=64 K=128
    f32x4 acc3[4] = {};
    #pragma unroll
    for (int mt = 0; mt < 4; ++mt) {
      const int h = 16 * mt + bl;
      #pragma unroll
      for (int kc = 0; kc < 4; ++kc) {
        frag_u a;
        a.u = *(const u32x4*)(wt3 + h * 256 + 16 * ((4 * kc + bq) ^ (h & 7)));
        acc3[mt] = __builtin_amdgcn_mfma_f32_16x16x32_bf16(a.h, b3[kc].h, acc3[mt], 0, 0, 0);
      }
    }

    // ---- relu + store: regs 0..3 are 4 consecutive h -> coalesced f32x4
    float* po = out + brow * GH3 + g * 64 + 4 * bq;
    #pragma unroll
    for (int mt = 0; mt < 4; ++mt) {
      f32x4 v = acc3[mt];
      v[0] = fmaxf(v[0], 0.f); v[1] = fmaxf(v[1], 0.f);
      v[2] = fmaxf(v[2], 0.f); v[3] = fmaxf(v[3], 0.f);
      *(f32x4*)(po + 16 * mt) = v;
    }
  }
}

extern "C" void kernel_launch(void* const* d_in, const int* in_sizes, int n_in,
                              void* d_out, int out_size, void* d_ws, size_t ws_size,
                              hipStream_t stream) {
  const float* x  = (const float*)d_in[0];
  const float* w1 = (const float*)d_in[1];
  const float* w2 = (const float*)d_in[2];
  const float* w3 = (const float*)d_in[3];
  float* out = (float*)d_out;
  (void)in_sizes; (void)n_in; (void)out_size; (void)d_ws; (void)ws_size;
  DeepBlockDense_kernel<<<dim3(NG), dim3(512), 0, stream>>>(x, w1, w2, w3, out);
}